// Round 5
// baseline (207.119 us; speedup 1.0000x reference)
//
#include <hip/hip_runtime.h>

// ---------------- workspace float layout ----------------
// [0]                gmax (ordered-uint encoding, memset to 0)
// [16 .. 616)        consts: (o*20+h)*6 + {mean0, rstd0, cc0, mean1, rstd1, cc1}
// [640 .. 645)       baseW[o] = sum_ij log_w[o,i,j,0]
// [656 .. 2656)      lwd[o][i][j] = lw0 - lw1
// [4096 .. 14336)    W1t[k][j]  (512 x 20)
// [16384 .. 671744)  h_t[j][b]  (20 x 32768)
// [671744 .. 835584) y_t[o][b]  (5 x 32768)
#define OFF_CST   16
#define OFF_BASEW 640
#define OFF_LWD   656
#define OFF_W1T   4096
#define OFF_HT    16384
#define OFF_YT    (16384 + 20*32768)
#define NB        32768

__device__ __forceinline__ unsigned enc_f(float f) {
  unsigned u = __float_as_uint(f);
  return (u & 0x80000000u) ? ~u : (u | 0x80000000u);
}
__device__ __forceinline__ float dec_f(unsigned u) {
  return __uint_as_float((u & 0x80000000u) ? (u & 0x7fffffffu) : ~u);
}

// ---------------- K0: prep (transpose W1, leaf consts, lwd, baseW) ----------------
__global__ void k0_prep(const float* __restrict__ W1,
                        const float* __restrict__ m0, const float* __restrict__ s0,
                        const float* __restrict__ m1, const float* __restrict__ s1,
                        const float* __restrict__ lw, float* __restrict__ wf) {
  int t = threadIdx.x;                    // 320 threads, 5 waves
  for (int idx = t; idx < 10240; idx += 320) {
    int k = idx / 20, j = idx - k * 20;
    wf[OFF_W1T + idx] = W1[j * 512 + k];
  }
  if (t < 100) {
    float sd0 = s0[t], sd1 = s1[t];
    float* c = wf + OFF_CST + t * 6;
    c[0] = m0[t]; c[1] = 1.0f / sd0; c[2] = -logf(sd0) - 0.91893853320467267f;
    c[3] = m1[t]; c[4] = 1.0f / sd1; c[5] = -logf(sd1) - 0.91893853320467267f;
  }
  int wv = t >> 6, ln = t & 63;           // wave wv handles o = wv
  float sum = 0.f;
  for (int p = ln; p < 400; p += 64) {
    float w0 = lw[(wv * 400 + p) * 2];
    float w1 = lw[(wv * 400 + p) * 2 + 1];
    wf[OFF_LWD + wv * 400 + p] = w0 - w1;
    sum += w0;
  }
  #pragma unroll
  for (int off = 32; off; off >>= 1) sum += __shfl_xor(sum, off);
  if (ln == 0) wf[OFF_BASEW + wv] = sum;
}

// ---------------- K1: fc1 + ReLU, split-K x4, h stored transposed ----------------
__global__ __launch_bounds__(256) void k1_fc1(
    const float* __restrict__ x, const float* __restrict__ b1,
    const float* __restrict__ wf, float* __restrict__ ht) {
  __shared__ float red[4 * 64 * 21];
  int t = threadIdx.x;
  int r = t & 63, kq = t >> 6;            // row-in-block, k-quarter (wave-uniform)
  size_t row = (size_t)blockIdx.x * 64 + r;
  const float4* xp = (const float4*)(x + row * 512 + kq * 128);
  const float* wt = wf + OFF_W1T + kq * 128 * 20;
  float acc[20];
  #pragma unroll
  for (int j = 0; j < 20; ++j) acc[j] = 0.f;
  #pragma unroll 4
  for (int q = 0; q < 32; ++q) {
    float4 xv = xp[q];
    const float* wp = wt + q * 80;
    #pragma unroll
    for (int j = 0; j < 20; ++j) acc[j] = fmaf(xv.x, wp[j], acc[j]);
    #pragma unroll
    for (int j = 0; j < 20; ++j) acc[j] = fmaf(xv.y, wp[20 + j], acc[j]);
    #pragma unroll
    for (int j = 0; j < 20; ++j) acc[j] = fmaf(xv.z, wp[40 + j], acc[j]);
    #pragma unroll
    for (int j = 0; j < 20; ++j) acc[j] = fmaf(xv.w, wp[60 + j], acc[j]);
  }
  float* rp = red + (kq * 64 + r) * 21;
  #pragma unroll
  for (int j = 0; j < 20; ++j) rp[j] = acc[j];
  __syncthreads();
  int jg = t >> 6;                        // wave-uniform j-group
  #pragma unroll
  for (int u = 0; u < 5; ++u) {
    int j = jg * 5 + u;
    float s = red[(0 * 64 + r) * 21 + j] + red[(1 * 64 + r) * 21 + j]
            + red[(2 * 64 + r) * 21 + j] + red[(3 * 64 + r) * 21 + j];
    s += b1[j];
    ht[j * NB + blockIdx.x * 64 + r] = fmaxf(s, 0.f);
  }
}

// ---------------- K2: SPN per (b, o), factored sum + product-batched log1p ----------------
__global__ __launch_bounds__(256) void k2_spn(
    const float* __restrict__ wf, float* __restrict__ yt, unsigned* __restrict__ gm) {
  __shared__ float dl[20][256];
  int t = threadIdx.x;
  int o = blockIdx.y;                     // wave/block-uniform -> scalar const loads
  size_t b = (size_t)blockIdx.x * 256 + t;
  const float* ht = wf + OFF_HT;
  const float* c = wf + OFF_CST + o * 120;
  float delta[20];
  float sL0 = 0.f;
  #pragma unroll
  for (int j = 0; j < 20; ++j) {
    float hv = ht[j * NB + b];
    float z0 = (hv - c[j * 6 + 0]) * c[j * 6 + 1];
    float L0 = fmaf(z0, -0.5f * z0, c[j * 6 + 2]);
    float z1 = (hv - c[j * 6 + 3]) * c[j * 6 + 4];
    float L1 = fmaf(z1, -0.5f * z1, c[j * 6 + 5]);
    float dj = L0 - L1;
    delta[j] = dj;
    dl[j][t] = dj;                        // same-thread write/read, no barrier needed
    sL0 += L0;
  }
  float baseA = fmaf(40.f, sL0, wf[OFF_BASEW + o]);
  const float* lwd = wf + OFF_LWD + o * 400;
  float accMin = 0.f, accLn = 0.f;
  #pragma unroll 4
  for (int i = 0; i < 20; ++i) {
    float di = dl[i][t];
    const float* lwp = lwd + i * 20;
    float p0 = 1.f, p1 = 1.f, mn0 = 0.f, mn1 = 0.f;
    #pragma unroll
    for (int j = 0; j < 20; ++j) {
      float d = (lwp[j] + di) + delta[j];
      float mnd = fminf(d, 0.f);
      float e = __expf(-fabsf(d));
      float u = 1.f + e;
      if (j & 1) { mn1 += mnd; p1 *= u; } else { mn0 += mnd; p0 *= u; }
    }
    accMin += mn0 + mn1;
    accLn += __logf(p0 * p1);
  }
  float root = baseA - accMin + accLn;
  float y = __logf(-root);
  yt[o * NB + b] = y;
  float m = y;
  #pragma unroll
  for (int off = 32; off; off >>= 1) m = fmaxf(m, __shfl_xor(m, off));
  if ((t & 63) == 0) atomicMax(gm, enc_f(m));
}

// ---------------- K3: out = sigmoid((gmax - y) @ W2 + b2) ----------------
__global__ __launch_bounds__(256) void k3_out(
    const float* __restrict__ wf, const unsigned* __restrict__ gm,
    const float* __restrict__ W2, const float* __restrict__ b2,
    float* __restrict__ out) {
  size_t b = (size_t)blockIdx.x * 256 + threadIdx.x;
  float g = dec_f(*gm);
  const float* yt = wf + OFF_YT;
  float acc = b2[0];
  #pragma unroll
  for (int o = 0; o < 5; ++o)
    acc += (g - yt[o * NB + b]) * W2[o];
  out[b] = 1.0f / (1.0f + __expf(-acc));
}

extern "C" void kernel_launch(void* const* d_in, const int* in_sizes, int n_in,
                              void* d_out, int out_size, void* d_ws, size_t ws_size,
                              hipStream_t stream) {
  const float* x  = (const float*)d_in[0];
  const float* W1 = (const float*)d_in[1];
  const float* b1 = (const float*)d_in[2];
  const float* m0 = (const float*)d_in[3];
  const float* s0 = (const float*)d_in[4];
  const float* m1 = (const float*)d_in[5];
  const float* s1 = (const float*)d_in[6];
  const float* lw = (const float*)d_in[7];
  const float* W2 = (const float*)d_in[8];
  const float* b2 = (const float*)d_in[9];
  float* wf = (float*)d_ws;
  float* out = (float*)d_out;

  hipMemsetAsync(d_ws, 0, 16, stream);   // gmax identity (encodes below any finite float)
  k0_prep<<<1, 320, 0, stream>>>(W1, m0, s0, m1, s1, lw, wf);
  k1_fc1<<<512, 256, 0, stream>>>(x, b1, wf, wf + OFF_HT);
  k2_spn<<<dim3(128, 5), 256, 0, stream>>>(wf, wf + OFF_YT, (unsigned*)d_ws);
  k3_out<<<NB / 256, 256, 0, stream>>>(wf, (const unsigned*)d_ws, W2, b2, out);
}

// Round 10
// 152.041 us; speedup vs baseline: 1.3623x; 1.3623x over previous
//
#include <hip/hip_runtime.h>

// ---------------- workspace float layout ----------------
// [0]                gmax (ordered-uint encoding, zeroed by k0)
// [16 .. 616)        consts: (o*20+h)*6 + {mean0, rstd0, cc0, mean1, rstd1, cc1}
// [640 .. 645)       baseW[o] = sum_ij log_w[o,i,j,0]
// [656 .. 2656)      lwd[o][i][j] = lw0 - lw1
// [4096 .. 14336)    W1t[k][j]  (512 x 20)
// [16384 .. 671744)  h_t[j][b]  (20 x 32768)
// [671744 .. 835584) y_t[o][b]  (5 x 32768)
#define OFF_CST   16
#define OFF_BASEW 640
#define OFF_LWD   656
#define OFF_W1T   4096
#define OFF_HT    16384
#define OFF_YT    (16384 + 20*32768)
#define NB        32768

__device__ __forceinline__ unsigned enc_f(float f) {
  unsigned u = __float_as_uint(f);
  return (u & 0x80000000u) ? ~u : (u | 0x80000000u);
}
__device__ __forceinline__ float dec_f(unsigned u) {
  return __uint_as_float((u & 0x80000000u) ? (u & 0x7fffffffu) : ~u);
}

// ---------------- K0: prep (transpose W1 coalesced-read, leaf consts, lwd, baseW, gm=0) ----
__global__ void k0_prep(const float* __restrict__ W1,
                        const float* __restrict__ m0, const float* __restrict__ s0,
                        const float* __restrict__ m1, const float* __restrict__ s1,
                        const float* __restrict__ lw, float* __restrict__ wf) {
  int t = threadIdx.x;                    // 320 threads, 5 waves
  if (t == 0) ((unsigned*)wf)[0] = 0u;    // gmax identity (below enc of any finite float)
  for (int idx = t; idx < 10240; idx += 320) {
    int j = idx >> 9, k = idx & 511;      // idx = j*512 + k: coalesced READ, scattered store
    wf[OFF_W1T + k * 20 + j] = W1[idx];
  }
  if (t < 100) {
    float sd0 = s0[t], sd1 = s1[t];
    float* c = wf + OFF_CST + t * 6;
    c[0] = m0[t]; c[1] = 1.0f / sd0; c[2] = -logf(sd0) - 0.91893853320467267f;
    c[3] = m1[t]; c[4] = 1.0f / sd1; c[5] = -logf(sd1) - 0.91893853320467267f;
  }
  int wv = t >> 6, ln = t & 63;           // wave wv handles o = wv
  float sum = 0.f;
  for (int p = ln; p < 400; p += 64) {
    float w0 = lw[(wv * 400 + p) * 2];
    float w1 = lw[(wv * 400 + p) * 2 + 1];
    wf[OFF_LWD + wv * 400 + p] = w0 - w1;
    sum += w0;
  }
  #pragma unroll
  for (int off = 32; off; off >>= 1) sum += __shfl_xor(sum, off);
  if (ln == 0) wf[OFF_BASEW + wv] = sum;
}

// ---------------- K1: fc1 + ReLU, split-K x8, scalar W loads, h stored transposed -------
__global__ __launch_bounds__(512, 4) void k1_fc1(
    const float* __restrict__ x, const float* __restrict__ b1,
    const float* __restrict__ wf, float* __restrict__ ht) {
  __shared__ float red[8 * 64 * 21];      // 43008 B
  int t = threadIdx.x;
  int r = t & 63;
  // readfirstlane -> SGPR: W-tile address provably uniform -> s_load, not vector broadcast
  int kq = __builtin_amdgcn_readfirstlane(t >> 6);   // 0..7, 64 k-floats each
  size_t row = (size_t)blockIdx.x * 64 + r;
  const float4* xp = (const float4*)(x + row * 512 + kq * 64);
  const float* wt = wf + OFF_W1T + kq * 64 * 20;
  // issue all 16 x-loads as one independent clause (16 KB/wave in flight)
  float4 xv[16];
  #pragma unroll
  for (int q = 0; q < 16; ++q) xv[q] = xp[q];
  float acc[20];
  #pragma unroll
  for (int j = 0; j < 20; ++j) acc[j] = 0.f;
  #pragma unroll
  for (int q = 0; q < 16; ++q) {
    const float* wp = wt + q * 80;
    #pragma unroll
    for (int j = 0; j < 20; ++j) acc[j] = fmaf(xv[q].x, wp[j], acc[j]);
    #pragma unroll
    for (int j = 0; j < 20; ++j) acc[j] = fmaf(xv[q].y, wp[20 + j], acc[j]);
    #pragma unroll
    for (int j = 0; j < 20; ++j) acc[j] = fmaf(xv[q].z, wp[40 + j], acc[j]);
    #pragma unroll
    for (int j = 0; j < 20; ++j) acc[j] = fmaf(xv[q].w, wp[60 + j], acc[j]);
  }
  float* rp = red + (kq * 64 + r) * 21;   // stride 21: 2-way bank alias (free)
  #pragma unroll
  for (int j = 0; j < 20; ++j) rp[j] = acc[j];
  __syncthreads();
  for (int idx = t; idx < 1280; idx += 512) {
    int r2 = idx & 63, j = idx >> 6;      // one full wave = one j, 64 consecutive r2
    float s = b1[j];
    #pragma unroll
    for (int k = 0; k < 8; ++k) s += red[(k * 64 + r2) * 21 + j];
    ht[j * NB + blockIdx.x * 64 + r2] = fmaxf(s, 0.f);
  }
}

// ---------------- K2: SPN per (b, o), factored sum + product-batched log1p -------------
__global__ __launch_bounds__(256) void k2_spn(
    const float* __restrict__ wf, float* __restrict__ yt, unsigned* __restrict__ gm) {
  __shared__ float dl[20][256];
  __shared__ float wmax[4];
  int t = threadIdx.x;
  int o = blockIdx.y;                     // block-uniform -> scalar const loads
  size_t b = (size_t)blockIdx.x * 256 + t;
  const float* ht = wf + OFF_HT;
  const float* c = wf + OFF_CST + o * 120;
  float delta[20];
  float sL0 = 0.f;
  #pragma unroll
  for (int j = 0; j < 20; ++j) {
    float hv = ht[j * NB + b];
    float z0 = (hv - c[j * 6 + 0]) * c[j * 6 + 1];
    float L0 = fmaf(z0, -0.5f * z0, c[j * 6 + 2]);
    float z1 = (hv - c[j * 6 + 3]) * c[j * 6 + 4];
    float L1 = fmaf(z1, -0.5f * z1, c[j * 6 + 5]);
    float dj = L0 - L1;
    delta[j] = dj;
    dl[j][t] = dj;                        // same-thread write/read, no barrier needed
    sL0 += L0;
  }
  float baseA = fmaf(40.f, sL0, wf[OFF_BASEW + o]);
  const float* lwd = wf + OFF_LWD + o * 400;
  float accMin = 0.f, accLn = 0.f;
  #pragma unroll 4
  for (int i = 0; i < 20; ++i) {
    float di = dl[i][t];
    const float* lwp = lwd + i * 20;
    float p0 = 1.f, p1 = 1.f, mn0 = 0.f, mn1 = 0.f;
    #pragma unroll
    for (int j = 0; j < 20; ++j) {
      float d = (lwp[j] + di) + delta[j];
      float mnd = fminf(d, 0.f);
      float e = __expf(-fabsf(d));
      float u = 1.f + e;
      if (j & 1) { mn1 += mnd; p1 *= u; } else { mn0 += mnd; p0 *= u; }
    }
    accMin += mn0 + mn1;
    accLn += __logf(p0 * p1);
  }
  float root = baseA - accMin + accLn;
  float y = __logf(-root);
  yt[o * NB + b] = y;
  float m = y;
  #pragma unroll
  for (int off = 32; off; off >>= 1) m = fmaxf(m, __shfl_xor(m, off));
  if ((t & 63) == 0) wmax[t >> 6] = m;
  __syncthreads();
  if (t == 0) {
    float mm = fmaxf(fmaxf(wmax[0], wmax[1]), fmaxf(wmax[2], wmax[3]));
    atomicMax(gm, enc_f(mm));             // 1 atomic per block (640 total)
  }
}

// ---------------- K3: out = sigmoid((gmax - y) @ W2 + b2) ----------------
__global__ __launch_bounds__(256) void k3_out(
    const float* __restrict__ wf, const unsigned* __restrict__ gm,
    const float* __restrict__ W2, const float* __restrict__ b2,
    float* __restrict__ out) {
  size_t b = (size_t)blockIdx.x * 256 + threadIdx.x;
  float g = dec_f(*gm);
  const float* yt = wf + OFF_YT;
  float acc = b2[0];
  #pragma unroll
  for (int o = 0; o < 5; ++o)
    acc += (g - yt[o * NB + b]) * W2[o];
  out[b] = 1.0f / (1.0f + __expf(-acc));
}

extern "C" void kernel_launch(void* const* d_in, const int* in_sizes, int n_in,
                              void* d_out, int out_size, void* d_ws, size_t ws_size,
                              hipStream_t stream) {
  const float* x  = (const float*)d_in[0];
  const float* W1 = (const float*)d_in[1];
  const float* b1 = (const float*)d_in[2];
  const float* m0 = (const float*)d_in[3];
  const float* s0 = (const float*)d_in[4];
  const float* m1 = (const float*)d_in[5];
  const float* s1 = (const float*)d_in[6];
  const float* lw = (const float*)d_in[7];
  const float* W2 = (const float*)d_in[8];
  const float* b2 = (const float*)d_in[9];
  float* wf = (float*)d_ws;
  float* out = (float*)d_out;

  k0_prep<<<1, 320, 0, stream>>>(W1, m0, s0, m1, s1, lw, wf);
  k1_fc1<<<512, 512, 0, stream>>>(x, b1, wf, wf + OFF_HT);
  k2_spn<<<dim3(128, 5), 256, 0, stream>>>(wf, wf + OFF_YT, (unsigned*)d_ws);
  k3_out<<<NB / 256, 256, 0, stream>>>(wf, (const unsigned*)d_ws, W2, b2, out);
}

// Round 11
// 149.804 us; speedup vs baseline: 1.3826x; 1.0149x over previous
//
#include <hip/hip_runtime.h>

// ---------------- workspace float layout ----------------
// [0]                gmax (ordered-uint encoding, zeroed by k0 block 45)
// [16 .. 616)        consts: (o*20+h)*6 + {mean0, rstd0, cc0, mean1, rstd1, cc1}
// [640 .. 645)       baseW[o]  = sum_ij log_w[o,i,j,0]
// [648 .. 653)       lwdSum[o] = sum_ij (lw0 - lw1)            (natural units)
// [656 .. 2656)      lwd2[o][i][j] = (lw0 - lw1) * log2(e)     (log2 units)
// [4096 .. 14336)    W1t[k][j]  (512 x 20)
// [16384 .. 671744)  h_t[j][b]  (20 x 32768)
// [671744 .. 835584) y_t[o][b]  (5 x 32768)
#define OFF_CST   16
#define OFF_BASEW 640
#define OFF_SUMD  648
#define OFF_LWD   656
#define OFF_W1T   4096
#define OFF_HT    16384
#define OFF_YT    (16384 + 20*32768)
#define NB        32768
#define LOG2E     1.4426950408889634f
#define LN2       0.6931471805599453f

__device__ __forceinline__ unsigned enc_f(float f) {
  unsigned u = __float_as_uint(f);
  return (u & 0x80000000u) ? ~u : (u | 0x80000000u);
}
__device__ __forceinline__ float dec_f(unsigned u) {
  return __uint_as_float((u & 0x80000000u) ? (u & 0x7fffffffu) : ~u);
}

// ---------------- K0: parallel prep. 46 blocks x 256 ----------------
// blocks 0..39  : W1 transpose (coalesced read, scattered store) - 10240 lanes exact
// blocks 40..44 : o = blk-40: lwd2 row + baseW[o] + lwdSum[o] (block reduce)
// block  45     : leaf consts (t<100) + gmax zero (t==0)
__global__ __launch_bounds__(256) void k0_prep(
    const float* __restrict__ W1,
    const float* __restrict__ m0, const float* __restrict__ s0,
    const float* __restrict__ m1, const float* __restrict__ s1,
    const float* __restrict__ lw, float* __restrict__ wf) {
  int t = threadIdx.x, blk = blockIdx.x;
  if (blk < 40) {
    int idx = blk * 256 + t;              // 0..10239
    int j = idx >> 9, k = idx & 511;      // idx = j*512 + k
    wf[OFF_W1T + k * 20 + j] = W1[idx];
    return;
  }
  if (blk < 45) {
    int o = blk - 40;
    __shared__ float r0[4], r1[4];
    float s0w = 0.f, sdw = 0.f;
    for (int p = t; p < 400; p += 256) {
      float w0 = lw[(o * 400 + p) * 2];
      float w1 = lw[(o * 400 + p) * 2 + 1];
      wf[OFF_LWD + o * 400 + p] = (w0 - w1) * LOG2E;
      s0w += w0;
      sdw += w0 - w1;
    }
    #pragma unroll
    for (int off = 32; off; off >>= 1) {
      s0w += __shfl_xor(s0w, off);
      sdw += __shfl_xor(sdw, off);
    }
    int wv = t >> 6;
    if ((t & 63) == 0) { r0[wv] = s0w; r1[wv] = sdw; }
    __syncthreads();
    if (t == 0) {
      wf[OFF_BASEW + o] = r0[0] + r0[1] + r0[2] + r0[3];
      wf[OFF_SUMD  + o] = r1[0] + r1[1] + r1[2] + r1[3];
    }
    return;
  }
  // blk == 45
  if (t == 0) ((unsigned*)wf)[0] = 0u;    // gmax identity
  if (t < 100) {
    float sd0 = s0[t], sd1 = s1[t];
    float* c = wf + OFF_CST + t * 6;
    c[0] = m0[t]; c[1] = 1.0f / sd0; c[2] = -logf(sd0) - 0.91893853320467267f;
    c[3] = m1[t]; c[4] = 1.0f / sd1; c[5] = -logf(sd1) - 0.91893853320467267f;
  }
}

// ---------------- K1: fc1 + ReLU, split-K x8, scalar W loads, h stored transposed -------
__global__ __launch_bounds__(512, 4) void k1_fc1(
    const float* __restrict__ x, const float* __restrict__ b1,
    const float* __restrict__ wf, float* __restrict__ ht) {
  __shared__ float red[8 * 64 * 21];      // 43008 B
  int t = threadIdx.x;
  int r = t & 63;
  int kq = __builtin_amdgcn_readfirstlane(t >> 6);   // 0..7, 64 k-floats each
  size_t row = (size_t)blockIdx.x * 64 + r;
  const float4* xp = (const float4*)(x + row * 512 + kq * 64);
  const float* wt = wf + OFF_W1T + kq * 64 * 20;
  float4 xv[16];
  #pragma unroll
  for (int q = 0; q < 16; ++q) xv[q] = xp[q];
  float acc[20];
  #pragma unroll
  for (int j = 0; j < 20; ++j) acc[j] = 0.f;
  #pragma unroll
  for (int q = 0; q < 16; ++q) {
    const float* wp = wt + q * 80;
    #pragma unroll
    for (int j = 0; j < 20; ++j) acc[j] = fmaf(xv[q].x, wp[j], acc[j]);
    #pragma unroll
    for (int j = 0; j < 20; ++j) acc[j] = fmaf(xv[q].y, wp[20 + j], acc[j]);
    #pragma unroll
    for (int j = 0; j < 20; ++j) acc[j] = fmaf(xv[q].z, wp[40 + j], acc[j]);
    #pragma unroll
    for (int j = 0; j < 20; ++j) acc[j] = fmaf(xv[q].w, wp[60 + j], acc[j]);
  }
  float* rp = red + (kq * 64 + r) * 21;
  #pragma unroll
  for (int j = 0; j < 20; ++j) rp[j] = acc[j];
  __syncthreads();
  for (int idx = t; idx < 1280; idx += 512) {
    int r2 = idx & 63, j = idx >> 6;
    float s = b1[j];
    #pragma unroll
    for (int k = 0; k < 8; ++k) s += red[(k * 64 + r2) * 21 + j];
    ht[j * NB + blockIdx.x * 64 + r2] = fmaxf(s, 0.f);
  }
}

// ---------------- K2: SPN per (b, o) in log2 domain ------------------------------------
// Sum S = baseA - accMin + accLn;  accMin = (lwdSum + 40*sDelta - Sum|d|)/2 (closed form)
// log2 domain: d2 = lwd2 + delta2_i + delta2_j -> exp2f(-|d2|) needs no scale mul.
__global__ __launch_bounds__(256) void k2_spn(
    const float* __restrict__ wf, float* __restrict__ yt, unsigned* __restrict__ gm) {
  __shared__ float dl[20][256];
  __shared__ float wmax[4];
  int t = threadIdx.x;
  int o = blockIdx.y;                     // block-uniform -> scalar const loads
  size_t b = (size_t)blockIdx.x * 256 + t;
  const float* ht = wf + OFF_HT;
  const float* c = wf + OFF_CST + o * 120;
  float d2[20];
  float sL0 = 0.f, sd2 = 0.f;
  #pragma unroll
  for (int j = 0; j < 20; ++j) {
    float hv = ht[j * NB + b];
    float z0 = (hv - c[j * 6 + 0]) * c[j * 6 + 1];
    float L0 = fmaf(z0, -0.5f * z0, c[j * 6 + 2]);
    float z1 = (hv - c[j * 6 + 3]) * c[j * 6 + 4];
    float L1 = fmaf(z1, -0.5f * z1, c[j * 6 + 5]);
    float dj2 = (L0 - L1) * LOG2E;
    d2[j] = dj2;
    dl[j][t] = dj2;                       // same-thread write/read, no barrier needed
    sL0 += L0;
    sd2 += dj2;
  }
  float baseA = fmaf(40.f, sL0, wf[OFF_BASEW + o]);
  const float* lwd2 = wf + OFF_LWD + o * 400;
  float aAbs0 = 0.f, aAbs1 = 0.f, accL2 = 0.f;
  #pragma unroll 4
  for (int i = 0; i < 20; ++i) {
    float di = dl[i][t];
    const float* lwp = lwd2 + i * 20;
    float p0 = 1.f, p1 = 1.f;
    #pragma unroll
    for (int j = 0; j < 20; ++j) {
      float d = (lwp[j] + di) + d2[j];    // log2 units
      float e = exp2f(-fabsf(d));         // v_exp_f32 with neg+abs input modifiers
      float u = 1.f + e;
      if (j & 1) { aAbs1 += fabsf(d); p1 *= u; }
      else       { aAbs0 += fabsf(d); p0 *= u; }
    }
    accL2 += __log2f(p0 * p1);
  }
  float accAbs2 = aAbs0 + aAbs1;          // = Sum|d| * log2e
  float lwdSum = wf[OFF_SUMD + o];
  // accMin = 0.5*(lwdSum + LN2*(40*sd2 - accAbs2));  accLn = LN2*accL2
  float root = baseA - 0.5f * (lwdSum + LN2 * (40.f * sd2 - accAbs2)) + LN2 * accL2;
  float y = __logf(-root);
  yt[o * NB + b] = y;
  float m = y;
  #pragma unroll
  for (int off = 32; off; off >>= 1) m = fmaxf(m, __shfl_xor(m, off));
  if ((t & 63) == 0) wmax[t >> 6] = m;
  __syncthreads();
  if (t == 0) {
    float mm = fmaxf(fmaxf(wmax[0], wmax[1]), fmaxf(wmax[2], wmax[3]));
    atomicMax(gm, enc_f(mm));             // 1 atomic per block (640 total)
  }
}

// ---------------- K3: out = sigmoid((gmax - y) @ W2 + b2) ----------------
__global__ __launch_bounds__(256) void k3_out(
    const float* __restrict__ wf, const unsigned* __restrict__ gm,
    const float* __restrict__ W2, const float* __restrict__ b2,
    float* __restrict__ out) {
  size_t b = (size_t)blockIdx.x * 256 + threadIdx.x;
  float g = dec_f(*gm);
  const float* yt = wf + OFF_YT;
  float acc = b2[0];
  #pragma unroll
  for (int o = 0; o < 5; ++o)
    acc += (g - yt[o * NB + b]) * W2[o];
  out[b] = 1.0f / (1.0f + __expf(-acc));
}

extern "C" void kernel_launch(void* const* d_in, const int* in_sizes, int n_in,
                              void* d_out, int out_size, void* d_ws, size_t ws_size,
                              hipStream_t stream) {
  const float* x  = (const float*)d_in[0];
  const float* W1 = (const float*)d_in[1];
  const float* b1 = (const float*)d_in[2];
  const float* m0 = (const float*)d_in[3];
  const float* s0 = (const float*)d_in[4];
  const float* m1 = (const float*)d_in[5];
  const float* s1 = (const float*)d_in[6];
  const float* lw = (const float*)d_in[7];
  const float* W2 = (const float*)d_in[8];
  const float* b2 = (const float*)d_in[9];
  float* wf = (float*)d_ws;
  float* out = (float*)d_out;

  k0_prep<<<46, 256, 0, stream>>>(W1, m0, s0, m1, s1, lw, wf);
  k1_fc1<<<512, 512, 0, stream>>>(x, b1, wf, wf + OFF_HT);
  k2_spn<<<dim3(128, 5), 256, 0, stream>>>(wf, wf + OFF_YT, (unsigned*)d_ws);
  k3_out<<<NB / 256, 256, 0, stream>>>(wf, (const unsigned*)d_ws, W2, b2, out);
}

// Round 12
// 147.124 us; speedup vs baseline: 1.4078x; 1.0182x over previous
//
#include <hip/hip_runtime.h>

// ---------------- workspace float layout ----------------
// [0]                gmax (ordered-uint encoding, zeroed by k0 block 45)
// [16 .. 616)        consts: (o*20+h)*6 + {mean0, rstd0, cc0, mean1, rstd1, cc1}
// [640 .. 645)       baseW[o]  = sum_ij log_w[o,i,j,0]
// [648 .. 653)       lwdSum[o] = sum_ij (lw0 - lw1)            (natural units)
// [656 .. 2656)      lwd2[o][i][j] = (lw0 - lw1) * log2(e)     (log2 units)
// [4096 .. 14336)    W1t[k][j]  (512 x 20)
// [16384 .. 671744)  h_t[j][b]  (20 x 32768)
// [671744 .. 835584) y_t[o][b]  (5 x 32768)
#define OFF_CST   16
#define OFF_BASEW 640
#define OFF_SUMD  648
#define OFF_LWD   656
#define OFF_W1T   4096
#define OFF_HT    16384
#define OFF_YT    (16384 + 20*32768)
#define NB        32768
#define LOG2E     1.4426950408889634f
#define LN2       0.6931471805599453f

__device__ __forceinline__ unsigned enc_f(float f) {
  unsigned u = __float_as_uint(f);
  return (u & 0x80000000u) ? ~u : (u | 0x80000000u);
}
__device__ __forceinline__ float dec_f(unsigned u) {
  return __uint_as_float((u & 0x80000000u) ? (u & 0x7fffffffu) : ~u);
}

// ---------------- K0: parallel prep. 46 blocks x 256 ----------------
__global__ __launch_bounds__(256) void k0_prep(
    const float* __restrict__ W1,
    const float* __restrict__ m0, const float* __restrict__ s0,
    const float* __restrict__ m1, const float* __restrict__ s1,
    const float* __restrict__ lw, float* __restrict__ wf) {
  int t = threadIdx.x, blk = blockIdx.x;
  if (blk < 40) {
    int idx = blk * 256 + t;              // 0..10239
    int j = idx >> 9, k = idx & 511;      // idx = j*512 + k
    wf[OFF_W1T + k * 20 + j] = W1[idx];
    return;
  }
  if (blk < 45) {
    int o = blk - 40;
    __shared__ float r0[4], r1[4];
    float s0w = 0.f, sdw = 0.f;
    for (int p = t; p < 400; p += 256) {
      float w0 = lw[(o * 400 + p) * 2];
      float w1 = lw[(o * 400 + p) * 2 + 1];
      wf[OFF_LWD + o * 400 + p] = (w0 - w1) * LOG2E;
      s0w += w0;
      sdw += w0 - w1;
    }
    #pragma unroll
    for (int off = 32; off; off >>= 1) {
      s0w += __shfl_xor(s0w, off);
      sdw += __shfl_xor(sdw, off);
    }
    int wv = t >> 6;
    if ((t & 63) == 0) { r0[wv] = s0w; r1[wv] = sdw; }
    __syncthreads();
    if (t == 0) {
      wf[OFF_BASEW + o] = r0[0] + r0[1] + r0[2] + r0[3];
      wf[OFF_SUMD  + o] = r1[0] + r1[1] + r1[2] + r1[3];
    }
    return;
  }
  // blk == 45
  if (t == 0) ((unsigned*)wf)[0] = 0u;    // gmax identity
  if (t < 100) {
    float sd0 = s0[t], sd1 = s1[t];
    float* c = wf + OFF_CST + t * 6;
    c[0] = m0[t]; c[1] = 1.0f / sd0; c[2] = -logf(sd0) - 0.91893853320467267f;
    c[3] = m1[t]; c[4] = 1.0f / sd1; c[5] = -logf(sd1) - 0.91893853320467267f;
  }
}

// ---------------- K1: fc1 + ReLU, split-K x8, scalar W loads, h stored transposed -------
__global__ __launch_bounds__(512, 4) void k1_fc1(
    const float* __restrict__ x, const float* __restrict__ b1,
    const float* __restrict__ wf, float* __restrict__ ht) {
  __shared__ float red[8 * 64 * 21];      // 43008 B
  int t = threadIdx.x;
  int r = t & 63;
  int kq = __builtin_amdgcn_readfirstlane(t >> 6);   // 0..7, 64 k-floats each
  size_t row = (size_t)blockIdx.x * 64 + r;
  const float4* xp = (const float4*)(x + row * 512 + kq * 64);
  const float* wt = wf + OFF_W1T + kq * 64 * 20;
  float4 xv[16];
  #pragma unroll
  for (int q = 0; q < 16; ++q) xv[q] = xp[q];
  float acc[20];
  #pragma unroll
  for (int j = 0; j < 20; ++j) acc[j] = 0.f;
  #pragma unroll
  for (int q = 0; q < 16; ++q) {
    const float* wp = wt + q * 80;
    #pragma unroll
    for (int j = 0; j < 20; ++j) acc[j] = fmaf(xv[q].x, wp[j], acc[j]);
    #pragma unroll
    for (int j = 0; j < 20; ++j) acc[j] = fmaf(xv[q].y, wp[20 + j], acc[j]);
    #pragma unroll
    for (int j = 0; j < 20; ++j) acc[j] = fmaf(xv[q].z, wp[40 + j], acc[j]);
    #pragma unroll
    for (int j = 0; j < 20; ++j) acc[j] = fmaf(xv[q].w, wp[60 + j], acc[j]);
  }
  float* rp = red + (kq * 64 + r) * 21;
  #pragma unroll
  for (int j = 0; j < 20; ++j) rp[j] = acc[j];
  __syncthreads();
  for (int idx = t; idx < 1280; idx += 512) {
    int r2 = idx & 63, j = idx >> 6;
    float s = b1[j];
    #pragma unroll
    for (int k = 0; k < 8; ++k) s += red[(k * 64 + r2) * 21 + j];
    ht[j * NB + blockIdx.x * 64 + r2] = fmaxf(s, 0.f);
  }
}

// ---------------- K2: SPN per (b, o), log2 domain, lwd2 in LDS, FULL unroll -------------
// root = baseA - 0.5*(lwdSum + LN2*(40*sd2 - aAbs)) + LN2*accL2
__global__ __launch_bounds__(256) void k2_spn(
    const float* __restrict__ wf, float* __restrict__ yt, unsigned* __restrict__ gm) {
  __shared__ float lw2s[400];             // mixture row, broadcast-read
  __shared__ float wmax[4];
  int t = threadIdx.x;
  int o = blockIdx.y;                     // block-uniform
  size_t b = (size_t)blockIdx.x * 256 + t;
  const float* ht = wf + OFF_HT;
  const float* c = wf + OFF_CST + o * 120;
  const float* lwd2 = wf + OFF_LWD + o * 400;
  // stage lwd2 row into LDS; loads issue here, sync deferred past leaf phase
  if (t < 200) { lw2s[t] = lwd2[t]; lw2s[t + 200] = lwd2[t + 200]; }
  // ---- leaf phase: registers only ----
  float d2[20];
  float sL0 = 0.f, sd2 = 0.f;
  #pragma unroll
  for (int j = 0; j < 20; ++j) {
    float hv = ht[j * NB + b];
    float z0 = (hv - c[j * 6 + 0]) * c[j * 6 + 1];
    float L0 = fmaf(z0, -0.5f * z0, c[j * 6 + 2]);
    float z1 = (hv - c[j * 6 + 3]) * c[j * 6 + 4];
    float L1 = fmaf(z1, -0.5f * z1, c[j * 6 + 5]);
    float dj2 = (L0 - L1) * LOG2E;
    d2[j] = dj2;
    sL0 += L0;
    sd2 += dj2;
  }
  float baseA = fmaf(40.f, sL0, wf[OFF_BASEW + o]);
  __syncthreads();                        // lw2s ready (staging overlapped leaf)
  // ---- 400 pairs, fully unrolled: all indices compile-time ----
  float aA0 = 0.f, aA1 = 0.f, aA2 = 0.f, aA3 = 0.f, accL2 = 0.f;
  #pragma unroll
  for (int i = 0; i < 20; ++i) {
    float di = d2[i];
    float p0 = 1.f, p1 = 1.f;
    #pragma unroll
    for (int j = 0; j < 20; ++j) {
      float d = (lw2s[i * 20 + j] + di) + d2[j];
      float e = exp2f(-fabsf(d));         // v_exp_f32, input modifiers fold neg+abs
      float ad = fabsf(d);
      if ((j & 3) == 0) aA0 += ad; else if ((j & 3) == 1) aA1 += ad;
      else if ((j & 3) == 2) aA2 += ad; else aA3 += ad;
      if (j & 1) p1 *= 1.f + e; else p0 *= 1.f + e;
    }
    accL2 += __log2f(p0 * p1);
  }
  float aAbs = (aA0 + aA1) + (aA2 + aA3); // = Sum|d| in log2 units
  float lwdSum = wf[OFF_SUMD + o];
  float root = baseA - 0.5f * (lwdSum + LN2 * (40.f * sd2 - aAbs)) + LN2 * accL2;
  float y = __logf(-root);
  yt[o * NB + b] = y;
  float m = y;
  #pragma unroll
  for (int off = 32; off; off >>= 1) m = fmaxf(m, __shfl_xor(m, off));
  if ((t & 63) == 0) wmax[t >> 6] = m;
  __syncthreads();
  if (t == 0) {
    float mm = fmaxf(fmaxf(wmax[0], wmax[1]), fmaxf(wmax[2], wmax[3]));
    atomicMax(gm, enc_f(mm));             // 1 atomic per block (640 total)
  }
}

// ---------------- K3: out = sigmoid((gmax - y) @ W2 + b2) ----------------
__global__ __launch_bounds__(256) void k3_out(
    const float* __restrict__ wf, const unsigned* __restrict__ gm,
    const float* __restrict__ W2, const float* __restrict__ b2,
    float* __restrict__ out) {
  size_t b = (size_t)blockIdx.x * 256 + threadIdx.x;
  float g = dec_f(*gm);
  const float* yt = wf + OFF_YT;
  float acc = b2[0];
  #pragma unroll
  for (int o = 0; o < 5; ++o)
    acc += (g - yt[o * NB + b]) * W2[o];
  out[b] = 1.0f / (1.0f + __expf(-acc));
}

extern "C" void kernel_launch(void* const* d_in, const int* in_sizes, int n_in,
                              void* d_out, int out_size, void* d_ws, size_t ws_size,
                              hipStream_t stream) {
  const float* x  = (const float*)d_in[0];
  const float* W1 = (const float*)d_in[1];
  const float* b1 = (const float*)d_in[2];
  const float* m0 = (const float*)d_in[3];
  const float* s0 = (const float*)d_in[4];
  const float* m1 = (const float*)d_in[5];
  const float* s1 = (const float*)d_in[6];
  const float* lw = (const float*)d_in[7];
  const float* W2 = (const float*)d_in[8];
  const float* b2 = (const float*)d_in[9];
  float* wf = (float*)d_ws;
  float* out = (float*)d_out;

  k0_prep<<<46, 256, 0, stream>>>(W1, m0, s0, m1, s1, lw, wf);
  k1_fc1<<<512, 512, 0, stream>>>(x, b1, wf, wf + OFF_HT);
  k2_spn<<<dim3(128, 5), 256, 0, stream>>>(wf, wf + OFF_YT, (unsigned*)d_ws);
  k3_out<<<NB / 256, 256, 0, stream>>>(wf, (const unsigned*)d_ws, W2, b2, out);
}